// Round 8
// baseline (91.257 us; speedup 1.0000x reference)
//
#include <hip/hip_runtime.h>
#include <math.h>

// out = 0.05 * searchsorted(adc_char, clamp(x,0,7.9375), 'right') / 16
// x: 51,380,224 fp32; adc_char: 127 sorted thresholds.
//
// R8 = R6 (hybrid register-tree + bank-replicated-LDS search, exact-cover
// 1792-block grid, 1-deep software pipeline) with PLAIN stores instead of
// __builtin_nontemporal_store — isolating the store-policy variable.
// (R7's sc0/sc1/nt full-bypass stores broke coherence vs the harness's cached
// memset: stale zero lines in L2/MALL served the readback. Never bypass.)
// Pipe arithmetic says memory-bound with 3-4x slack on VALU/LDS; this A/B
// tests whether nt stores help (L3 residency of x) or hurt (write combining).

#define N_LEVELS 127
#define CLAMP_MAX 7.9375f
#define OUT_SCALE 0.003125f  // 0.05/16 exactly (exponent shift of fl(0.05f))

typedef float f32x4 __attribute__((ext_vector_type(4)));

struct TreeT {
    float T63;
    float T31, T95;
    float T15, T47, T79, T111;
    float Q0, Q1, Q2, Q3, Q4, Q5, Q6, Q7;  // th[16k+7]
};

__device__ __forceinline__ float adc_eval(const float* __restrict__ my,
                                          const TreeT& t, float x) {
    float a = fminf(fmaxf(x, 0.0f), CLAMP_MAX);   // v_med3_f32

    // Levels 0-3: register cndmask tree (w = 64, 32, 16, 8).
    bool m0 = (t.T63 <= a);
    float s1 = m0 ? t.T95 : t.T31;
    bool m1 = (s1 <= a);
    float u0 = m0 ? t.T79  : t.T15;
    float u1 = m0 ? t.T111 : t.T47;
    float s2 = m1 ? u1 : u0;
    bool m2 = (s2 <= a);
    float x0 = m2 ? t.Q1 : t.Q0;
    float x1 = m2 ? t.Q3 : t.Q2;
    float x2 = m2 ? t.Q5 : t.Q4;
    float x3 = m2 ? t.Q7 : t.Q6;
    float y0 = m1 ? x1 : x0;
    float y1 = m1 ? x3 : x2;
    float s3 = m0 ? y1 : y0;
    bool m3 = (s3 <= a);
    int cnt = (m0 ? 64 : 0) + (m1 ? 32 : 0) + (m2 ? 16 : 0) + (m3 ? 8 : 0);

    // Levels 4-6: bank-replicated LDS (w = 4, 2, 1) — conflict-free.
    if (my[(cnt + 3) << 5] <= a) cnt += 4;
    if (my[(cnt + 1) << 5] <= a) cnt += 2;
    if (my[(cnt + 0) << 5] <= a) cnt += 1;

    return OUT_SCALE * (float)cnt;
}

__device__ __forceinline__ void lut_fill(float* __restrict__ lut,
                                         const float* __restrict__ adc_char,
                                         int tid) {
    for (int i = tid; i < N_LEVELS * 32; i += 256) lut[i] = adc_char[i >> 5];
}

__device__ __forceinline__ TreeT tree_load(const float* __restrict__ adc_char) {
    TreeT t;
    t.T63 = adc_char[63];
    t.T31 = adc_char[31];  t.T95  = adc_char[95];
    t.T15 = adc_char[15];  t.T47  = adc_char[47];
    t.T79 = adc_char[79];  t.T111 = adc_char[111];
    t.Q0 = adc_char[7];    t.Q1 = adc_char[23];
    t.Q2 = adc_char[39];   t.Q3 = adc_char[55];
    t.Q4 = adc_char[71];   t.Q5 = adc_char[87];
    t.Q6 = adc_char[103];  t.Q7 = adc_char[119];
    return t;
}

// ---- exact-cover main: n4 == gridDim.x * 1024 * K, no predicates ----
__global__ __launch_bounds__(256) void adc_main_kernel(
        const float* __restrict__ x,
        float* __restrict__ out,
        const float* __restrict__ adc_char,
        int K) {
    __shared__ float lut[N_LEVELS * 32];  // 16256 B
    const int tid = threadIdx.x;
    lut_fill(lut, adc_char, tid);
    __syncthreads();
    const TreeT t = tree_load(adc_char);
    const float* my = lut + (tid & 31);

    const f32x4* __restrict__ x4 = (const f32x4*)x;
    f32x4* __restrict__ o4 = (f32x4*)out;

    int base = blockIdx.x * (K << 10) + tid;   // float4 units

    // software pipeline: loads for iter k+1 in flight during evals of iter k
    f32x4 v0 = x4[base], v1 = x4[base + 256], v2 = x4[base + 512], v3 = x4[base + 768];

    #define BODY(B)                                                         \
    {                                                                       \
        f32x4 r0, r1, r2, r3;                                               \
        r0.x = adc_eval(my, t, v0.x); r0.y = adc_eval(my, t, v0.y);         \
        r0.z = adc_eval(my, t, v0.z); r0.w = adc_eval(my, t, v0.w);         \
        r1.x = adc_eval(my, t, v1.x); r1.y = adc_eval(my, t, v1.y);         \
        r1.z = adc_eval(my, t, v1.z); r1.w = adc_eval(my, t, v1.w);         \
        r2.x = adc_eval(my, t, v2.x); r2.y = adc_eval(my, t, v2.y);         \
        r2.z = adc_eval(my, t, v2.z); r2.w = adc_eval(my, t, v2.w);         \
        r3.x = adc_eval(my, t, v3.x); r3.y = adc_eval(my, t, v3.y);         \
        r3.z = adc_eval(my, t, v3.z); r3.w = adc_eval(my, t, v3.w);         \
        o4[(B)]       = r0;                                                 \
        o4[(B) + 256] = r1;                                                 \
        o4[(B) + 512] = r2;                                                 \
        o4[(B) + 768] = r3;                                                 \
    }

    for (int k = 0; k < K - 1; ++k) {
        const int nb = base + 1024;
        f32x4 w0 = x4[nb], w1 = x4[nb + 256], w2 = x4[nb + 512], w3 = x4[nb + 768];
        BODY(base)
        v0 = w0; v1 = w1; v2 = w2; v3 = w3;
        base = nb;
    }
    BODY(base)
    #undef BODY
}

// ---- generic fallback (any n): grid-stride kernel ----
__global__ __launch_bounds__(256) void adc_generic_kernel(
        const float* __restrict__ x,
        const float* __restrict__ adc_char,
        float* __restrict__ out,
        int n4, int rem) {
    __shared__ float lut[N_LEVELS * 32];
    const int tid = threadIdx.x;
    lut_fill(lut, adc_char, tid);
    __syncthreads();
    const TreeT t = tree_load(adc_char);
    const float* my = lut + (tid & 31);

    const f32x4* __restrict__ x4 = (const f32x4*)x;
    f32x4* __restrict__ o4 = (f32x4*)out;

    const int stride = gridDim.x * 512;
    for (int i0 = blockIdx.x * 512 + tid; i0 < n4; i0 += stride) {
        const int i1 = i0 + 256;
        const bool p1 = i1 < n4;
        f32x4 v0 = x4[i0];
        f32x4 v1 = {0.f, 0.f, 0.f, 0.f};
        if (p1) v1 = x4[i1];
        f32x4 r0, r1;
        r0.x = adc_eval(my, t, v0.x); r0.y = adc_eval(my, t, v0.y);
        r0.z = adc_eval(my, t, v0.z); r0.w = adc_eval(my, t, v0.w);
        r1.x = adc_eval(my, t, v1.x); r1.y = adc_eval(my, t, v1.y);
        r1.z = adc_eval(my, t, v1.z); r1.w = adc_eval(my, t, v1.w);
        o4[i0] = r0;
        if (p1) o4[i1] = r1;
    }
    if (blockIdx.x == 0 && tid < rem) {
        int e = n4 * 4 + tid;
        out[e] = adc_eval(my, t, x[e]);
    }
}

extern "C" void kernel_launch(void* const* d_in, const int* in_sizes, int n_in,
                              void* d_out, int out_size, void* d_ws, size_t ws_size,
                              hipStream_t stream) {
    const float* x        = (const float*)d_in[0];
    const float* adc_char = (const float*)d_in[1];
    float* out            = (float*)d_out;

    const int n  = in_sizes[0];
    const int n4 = n >> 2;

    // exact-cover path: n4 = blocks * 1024 * K with blocks=1792 (7 blocks/CU).
    if ((n & 3) == 0 && n4 > 0 && (n4 % (1792 * 1024)) == 0) {
        const int K = n4 / (1792 * 1024);
        adc_main_kernel<<<1792, 256, 0, stream>>>(x, out, adc_char, K);
    } else {
        const int rem = n & 3;
        int gb = (n4 + 511) / 512;
        if (gb > 2048) gb = 2048;
        if (gb < 1) gb = 1;
        adc_generic_kernel<<<gb, 256, 0, stream>>>(x, adc_char, out, n4, rem);
    }
}

// Round 9
// 70.356 us; speedup vs baseline: 1.2971x; 1.2971x over previous
//
#include <hip/hip_runtime.h>
#include <math.h>

// out = 0.05 * searchsorted(adc_char, clamp(x,0,7.9375), 'right') / 16
// x: 51,380,224 fp32; adc_char: 127 sorted thresholds.
//
// R9 = R6 restored (proven best: 70.8 us = 92% of the 6.29 TB/s copy ceiling).
//  - hybrid eval: register cndmask tree (search levels 0-3, 15 wave-uniform
//    thresholds) + 32-way bank-replicated LDS LUT (levels 4-6). Bit-exact,
//    conflict-free (measured 0).
//  - exact-cover grid: 1792 blocks x 256 thr x 4 float4 x K=7, no predicates.
//  - 1-deep software pipeline (next iter's 4 float4 loads in flight).
//  - __builtin_nontemporal_store for the write-once output: coherent but
//    no-allocate -> x stays Infinity-Cache-resident across graph replays.
//    A/B: plain stores 91.3 us, nt 70.8 us (+20). sc0/sc1 full bypass BREAKS
//    coherence vs the harness's cached memset (R7 failure) - never bypass.

#define N_LEVELS 127
#define CLAMP_MAX 7.9375f
#define OUT_SCALE 0.003125f  // 0.05/16 exactly (exponent shift of fl(0.05f))

typedef float f32x4 __attribute__((ext_vector_type(4)));

struct TreeT {
    float T63;
    float T31, T95;
    float T15, T47, T79, T111;
    float Q0, Q1, Q2, Q3, Q4, Q5, Q6, Q7;  // th[16k+7]
};

__device__ __forceinline__ float adc_eval(const float* __restrict__ my,
                                          const TreeT& t, float x) {
    float a = fminf(fmaxf(x, 0.0f), CLAMP_MAX);   // v_med3_f32

    // Levels 0-3: register cndmask tree (w = 64, 32, 16, 8).
    bool m0 = (t.T63 <= a);
    float s1 = m0 ? t.T95 : t.T31;
    bool m1 = (s1 <= a);
    float u0 = m0 ? t.T79  : t.T15;
    float u1 = m0 ? t.T111 : t.T47;
    float s2 = m1 ? u1 : u0;
    bool m2 = (s2 <= a);
    float x0 = m2 ? t.Q1 : t.Q0;
    float x1 = m2 ? t.Q3 : t.Q2;
    float x2 = m2 ? t.Q5 : t.Q4;
    float x3 = m2 ? t.Q7 : t.Q6;
    float y0 = m1 ? x1 : x0;
    float y1 = m1 ? x3 : x2;
    float s3 = m0 ? y1 : y0;
    bool m3 = (s3 <= a);
    int cnt = (m0 ? 64 : 0) + (m1 ? 32 : 0) + (m2 ? 16 : 0) + (m3 ? 8 : 0);

    // Levels 4-6: bank-replicated LDS (w = 4, 2, 1) — conflict-free.
    if (my[(cnt + 3) << 5] <= a) cnt += 4;
    if (my[(cnt + 1) << 5] <= a) cnt += 2;
    if (my[(cnt + 0) << 5] <= a) cnt += 1;

    return OUT_SCALE * (float)cnt;
}

__device__ __forceinline__ void lut_fill(float* __restrict__ lut,
                                         const float* __restrict__ adc_char,
                                         int tid) {
    for (int i = tid; i < N_LEVELS * 32; i += 256) lut[i] = adc_char[i >> 5];
}

__device__ __forceinline__ TreeT tree_load(const float* __restrict__ adc_char) {
    TreeT t;
    t.T63 = adc_char[63];
    t.T31 = adc_char[31];  t.T95  = adc_char[95];
    t.T15 = adc_char[15];  t.T47  = adc_char[47];
    t.T79 = adc_char[79];  t.T111 = adc_char[111];
    t.Q0 = adc_char[7];    t.Q1 = adc_char[23];
    t.Q2 = adc_char[39];   t.Q3 = adc_char[55];
    t.Q4 = adc_char[71];   t.Q5 = adc_char[87];
    t.Q6 = adc_char[103];  t.Q7 = adc_char[119];
    return t;
}

// ---- exact-cover main: n4 == gridDim.x * 1024 * K, no predicates ----
__global__ __launch_bounds__(256) void adc_main_kernel(
        const float* __restrict__ x,
        float* __restrict__ out,
        const float* __restrict__ adc_char,
        int K) {
    __shared__ float lut[N_LEVELS * 32];  // 16256 B
    const int tid = threadIdx.x;
    lut_fill(lut, adc_char, tid);
    __syncthreads();
    const TreeT t = tree_load(adc_char);
    const float* my = lut + (tid & 31);

    const f32x4* __restrict__ x4 = (const f32x4*)x;
    f32x4* __restrict__ o4 = (f32x4*)out;

    int base = blockIdx.x * (K << 10) + tid;   // float4 units

    // software pipeline: loads for iter k+1 in flight during evals of iter k
    f32x4 v0 = x4[base], v1 = x4[base + 256], v2 = x4[base + 512], v3 = x4[base + 768];

    #define BODY(B)                                                         \
    {                                                                       \
        f32x4 r0, r1, r2, r3;                                               \
        r0.x = adc_eval(my, t, v0.x); r0.y = adc_eval(my, t, v0.y);         \
        r0.z = adc_eval(my, t, v0.z); r0.w = adc_eval(my, t, v0.w);         \
        r1.x = adc_eval(my, t, v1.x); r1.y = adc_eval(my, t, v1.y);         \
        r1.z = adc_eval(my, t, v1.z); r1.w = adc_eval(my, t, v1.w);         \
        r2.x = adc_eval(my, t, v2.x); r2.y = adc_eval(my, t, v2.y);         \
        r2.z = adc_eval(my, t, v2.z); r2.w = adc_eval(my, t, v2.w);         \
        r3.x = adc_eval(my, t, v3.x); r3.y = adc_eval(my, t, v3.y);         \
        r3.z = adc_eval(my, t, v3.z); r3.w = adc_eval(my, t, v3.w);         \
        __builtin_nontemporal_store(r0, &o4[(B)]);                          \
        __builtin_nontemporal_store(r1, &o4[(B) + 256]);                    \
        __builtin_nontemporal_store(r2, &o4[(B) + 512]);                    \
        __builtin_nontemporal_store(r3, &o4[(B) + 768]);                    \
    }

    for (int k = 0; k < K - 1; ++k) {
        const int nb = base + 1024;
        f32x4 w0 = x4[nb], w1 = x4[nb + 256], w2 = x4[nb + 512], w3 = x4[nb + 768];
        BODY(base)
        v0 = w0; v1 = w1; v2 = w2; v3 = w3;
        base = nb;
    }
    BODY(base)
    #undef BODY
}

// ---- generic fallback (any n): grid-stride kernel ----
__global__ __launch_bounds__(256) void adc_generic_kernel(
        const float* __restrict__ x,
        const float* __restrict__ adc_char,
        float* __restrict__ out,
        int n4, int rem) {
    __shared__ float lut[N_LEVELS * 32];
    const int tid = threadIdx.x;
    lut_fill(lut, adc_char, tid);
    __syncthreads();
    const TreeT t = tree_load(adc_char);
    const float* my = lut + (tid & 31);

    const f32x4* __restrict__ x4 = (const f32x4*)x;
    f32x4* __restrict__ o4 = (f32x4*)out;

    const int stride = gridDim.x * 512;
    for (int i0 = blockIdx.x * 512 + tid; i0 < n4; i0 += stride) {
        const int i1 = i0 + 256;
        const bool p1 = i1 < n4;
        f32x4 v0 = x4[i0];
        f32x4 v1 = {0.f, 0.f, 0.f, 0.f};
        if (p1) v1 = x4[i1];
        f32x4 r0, r1;
        r0.x = adc_eval(my, t, v0.x); r0.y = adc_eval(my, t, v0.y);
        r0.z = adc_eval(my, t, v0.z); r0.w = adc_eval(my, t, v0.w);
        r1.x = adc_eval(my, t, v1.x); r1.y = adc_eval(my, t, v1.y);
        r1.z = adc_eval(my, t, v1.z); r1.w = adc_eval(my, t, v1.w);
        o4[i0] = r0;
        if (p1) o4[i1] = r1;
    }
    if (blockIdx.x == 0 && tid < rem) {
        int e = n4 * 4 + tid;
        out[e] = adc_eval(my, t, x[e]);
    }
}

extern "C" void kernel_launch(void* const* d_in, const int* in_sizes, int n_in,
                              void* d_out, int out_size, void* d_ws, size_t ws_size,
                              hipStream_t stream) {
    const float* x        = (const float*)d_in[0];
    const float* adc_char = (const float*)d_in[1];
    float* out            = (float*)d_out;

    const int n  = in_sizes[0];
    const int n4 = n >> 2;

    // exact-cover path: n4 = blocks * 1024 * K with blocks=1792 (7 blocks/CU).
    if ((n & 3) == 0 && n4 > 0 && (n4 % (1792 * 1024)) == 0) {
        const int K = n4 / (1792 * 1024);
        adc_main_kernel<<<1792, 256, 0, stream>>>(x, out, adc_char, K);
    } else {
        const int rem = n & 3;
        int gb = (n4 + 511) / 512;
        if (gb > 2048) gb = 2048;
        if (gb < 1) gb = 1;
        adc_generic_kernel<<<gb, 256, 0, stream>>>(x, adc_char, out, n4, rem);
    }
}